// Round 2
// baseline (1123.354 us; speedup 1.0000x reference)
//
#include <hip/hip_runtime.h>
#include <cstdint>

#define NIN     2000
#define NRES    50
#define NOUT    500
#define TSTEPS  512
#define NBATCH  64
#define BT      32768   // NBATCH * TSTEPS

// tanh(x) = 1 - 2/(e^{2x}+1). Overflow-safe without clamping:
// x >> 0: e=inf -> rcp(inf)=0 -> 1 ; x << 0: e=0 -> 1-2 = -1. No NaN path.
__device__ __forceinline__ float fast_tanh(float x) {
  float e = __expf(2.0f * x);
  return fmaf(-2.0f, __builtin_amdgcn_rcpf(e + 1.0f), 1.0f);
}

// ---- kernel 1: P[bt][r] = sum_k tanh(u[bt][k]) * W_in[r][k]  (all fp32) ----
// block = 256 thr = 4 waves; block handles 128 rows of U.
// wave0: rows 0-63, r in [0,25); wave1: rows 0-63, r in [25,50);
// wave2: rows 64-127, r in [0,25); wave3: rows 64-127, r in [25,50).
// W addresses are wave-uniform (readfirstlane on rb) -> scalar s_load path;
// per-lane U stream gets a 1-iteration software prefetch.
__global__ __launch_bounds__(256) void proj_kernel(const float* __restrict__ U,
                                                   const float* __restrict__ Win,
                                                   float* __restrict__ P) {
  const int wave = threadIdx.x >> 6;
  const int lane = threadIdx.x & 63;
  const int row  = blockIdx.x * 128 + (wave >> 1) * 64 + lane;
  const int rb   = __builtin_amdgcn_readfirstlane((wave & 1) * 25);

  const float* __restrict__ u     = U + (size_t)row * NIN;
  const float* __restrict__ wbase = Win + (size_t)rb * NIN;

  float acc[25];
#pragma unroll
  for (int r = 0; r < 25; ++r) acc[r] = 0.0f;

  float4 c0 = *reinterpret_cast<const float4*>(u);
  float4 c1 = *reinterpret_cast<const float4*>(u + 4);

  for (int k0 = 0; k0 < NIN; k0 += 8) {
    // prefetch next 8 U elements (redundant reload on last iter keeps it in-bounds)
    const int kn = (k0 + 8 < NIN) ? (k0 + 8) : k0;
    float4 n0 = *reinterpret_cast<const float4*>(u + kn);
    float4 n1 = *reinterpret_cast<const float4*>(u + kn + 4);

    float t[8];
    t[0] = fast_tanh(c0.x); t[1] = fast_tanh(c0.y);
    t[2] = fast_tanh(c0.z); t[3] = fast_tanh(c0.w);
    t[4] = fast_tanh(c1.x); t[5] = fast_tanh(c1.y);
    t[6] = fast_tanh(c1.z); t[7] = fast_tanh(c1.w);

#pragma unroll
    for (int r = 0; r < 25; ++r) {
      const float* wr = wbase + r * NIN + k0;   // wave-uniform -> s_load_dwordx8
#pragma unroll
      for (int j = 0; j < 8; ++j)
        acc[r] = fmaf(t[j], wr[j], acc[r]);
    }
    c0 = n0; c1 = n1;
  }

  float* Prow = P + (size_t)row * NRES + rb;
#pragma unroll
  for (int r = 0; r < 25; ++r) Prow[r] = acc[r];
}

// ---- kernel 2: sequential recurrence (one wave per batch row) + fused readout ----
// lane r holds state[r] and W_res row r in registers; broadcast via v_readlane.
__global__ __launch_bounds__(64) void recur_kernel(const float* __restrict__ P,
                                                   const float* __restrict__ W_res,
                                                   const float* __restrict__ W_out,
                                                   const float* __restrict__ bias,
                                                   float* __restrict__ out) {
  const int b    = blockIdx.x;
  const int lane = threadIdx.x;
  const int r    = (lane < NRES) ? lane : 0;   // lanes 50-63 mirror lane 0 (never read back)

  float w[NRES];
#pragma unroll
  for (int j = 0; j < NRES; ++j) w[j] = W_res[r * NRES + j];

  const float* Pb = P + (size_t)b * TSTEPS * NRES;
  float state = 0.0f;
  float pcur  = Pb[r];

  for (int t = 0; t < TSTEPS; ++t) {
    // prefetch next step's P element so the L2 load stays off the serial chain
    float pnext = (t + 1 < TSTEPS) ? Pb[(t + 1) * NRES + r] : 0.0f;

    // 4-way split accumulator to shorten the serial FMA chain
    float a0 = pcur, a1 = 0.0f, a2 = 0.0f, a3 = 0.0f;
#pragma unroll
    for (int j = 0; j < 48; j += 4) {
      float s0 = __uint_as_float(__builtin_amdgcn_readlane(__float_as_uint(state), j + 0));
      float s1 = __uint_as_float(__builtin_amdgcn_readlane(__float_as_uint(state), j + 1));
      float s2 = __uint_as_float(__builtin_amdgcn_readlane(__float_as_uint(state), j + 2));
      float s3 = __uint_as_float(__builtin_amdgcn_readlane(__float_as_uint(state), j + 3));
      a0 = fmaf(s0, w[j + 0], a0);
      a1 = fmaf(s1, w[j + 1], a1);
      a2 = fmaf(s2, w[j + 2], a2);
      a3 = fmaf(s3, w[j + 3], a3);
    }
    {
      float s0 = __uint_as_float(__builtin_amdgcn_readlane(__float_as_uint(state), 48));
      float s1 = __uint_as_float(__builtin_amdgcn_readlane(__float_as_uint(state), 49));
      a0 = fmaf(s0, w[48], a0);
      a1 = fmaf(s1, w[49], a1);
    }
    state = fast_tanh((a0 + a1) + (a2 + a3));
    pcur  = pnext;
  }

  // readout: out[b][o] = tanh(sum_j state[j] * W_out[j][o] + bias[o])
#pragma unroll
  for (int kk = 0; kk < 8; ++kk) {
    int o = kk * 64 + lane;
    if (o < NOUT) {
      float a0 = bias[o];
      float a1 = 0.0f;
#pragma unroll
      for (int j = 0; j < NRES; j += 2) {
        float s0 = __uint_as_float(__builtin_amdgcn_readlane(__float_as_uint(state), j));
        float s1 = __uint_as_float(__builtin_amdgcn_readlane(__float_as_uint(state), j + 1));
        a0 = fmaf(s0, W_out[j * NOUT + o], a0);
        a1 = fmaf(s1, W_out[(j + 1) * NOUT + o], a1);
      }
      out[b * NOUT + o] = fast_tanh(a0 + a1);
    }
  }
}

extern "C" void kernel_launch(void* const* d_in, const int* in_sizes, int n_in,
                              void* d_out, int out_size, void* d_ws, size_t ws_size,
                              hipStream_t stream) {
  const float* inputs = (const float*)d_in[0];
  const float* W_in   = (const float*)d_in[1];
  const float* W_res  = (const float*)d_in[2];
  const float* W_out  = (const float*)d_in[3];
  const float* bias   = (const float*)d_in[4];
  float* out = (float*)d_out;

  // ws layout: P (f32 [32768][50]) at offset 0 — 6.55 MB
  float* P = (float*)d_ws;

  proj_kernel<<<BT / 128, 256, 0, stream>>>(inputs, W_in, P);
  recur_kernel<<<NBATCH, 64, 0, stream>>>(P, W_res, W_out, bias, out);
}

// Round 3
// 1036.169 us; speedup vs baseline: 1.0841x; 1.0841x over previous
//
#include <hip/hip_runtime.h>
#include <cstdint>

#define NIN     2000
#define NRES    50
#define NOUT    500
#define TSTEPS  512
#define NBATCH  64
#define BT      32768   // NBATCH * TSTEPS
#define KSPLIT  4
#define KCHUNK  512     // oct-groups of 8: 64,64,64,58

// tanh(x) = 1 - 2/(e^{2x}+1). Overflow-safe without clamping:
// x >> 0: e=inf -> rcp(inf)=0 -> 1 ; x << 0: e=0 -> 1-2 = -1. No NaN path.
__device__ __forceinline__ float fast_tanh(float x) {
  float e = __expf(2.0f * x);
  return fmaf(-2.0f, __builtin_amdgcn_rcpf(e + 1.0f), 1.0f);
}

// ---- kernel 0: zero P (harness poisons d_ws to 0xAA before every launch) ----
__global__ __launch_bounds__(256) void zero_kernel(float4* __restrict__ p, int n4) {
  int i = blockIdx.x * 256 + threadIdx.x;
  if (i < n4) p[i] = make_float4(0.f, 0.f, 0.f, 0.f);
}

// ---- kernel 1: P[bt][r] += sum_{k in chunk} tanh(u[bt][k]) * W_in[r][k] ----
// grid = (BT/128, KSPLIT). block = 256 thr = 4 waves; block handles 128 U-rows.
// wave0: rows 0-63, r in [0,25); wave1: rows 0-63, r in [25,50);
// wave2: rows 64-127, r in [0,25); wave3: rows 64-127, r in [25,50).
// k-split x4 gives 1024 blocks = 4 blocks/CU = 4 waves/SIMD so the scalar-load
// and HBM stalls of one wave interleave with compute of the other three.
// Partials combined with fp32 unsafeAtomicAdd (native global_atomic_add_f32).
__global__ __launch_bounds__(256) void proj_kernel(const float* __restrict__ U,
                                                   const float* __restrict__ Win,
                                                   float* __restrict__ P) {
  const int wave = threadIdx.x >> 6;
  const int lane = threadIdx.x & 63;
  const int row  = blockIdx.x * 128 + (wave >> 1) * 64 + lane;
  const int rb   = __builtin_amdgcn_readfirstlane((wave & 1) * 25);

  const int kbase = blockIdx.y * KCHUNK;
  const int kend  = (kbase + KCHUNK < NIN) ? (kbase + KCHUNK) : NIN;

  const float* __restrict__ u     = U + (size_t)row * NIN;
  const float* __restrict__ wbase = Win + (size_t)rb * NIN;

  float acc[25];
#pragma unroll
  for (int r = 0; r < 25; ++r) acc[r] = 0.0f;

  float4 c0 = *reinterpret_cast<const float4*>(u + kbase);
  float4 c1 = *reinterpret_cast<const float4*>(u + kbase + 4);

  for (int k0 = kbase; k0 < kend; k0 += 8) {
    // prefetch next 8 U elements (redundant reload on last iter keeps it in-bounds)
    const int kn = (k0 + 8 < kend) ? (k0 + 8) : k0;
    float4 n0 = *reinterpret_cast<const float4*>(u + kn);
    float4 n1 = *reinterpret_cast<const float4*>(u + kn + 4);

    float t[8];
    t[0] = fast_tanh(c0.x); t[1] = fast_tanh(c0.y);
    t[2] = fast_tanh(c0.z); t[3] = fast_tanh(c0.w);
    t[4] = fast_tanh(c1.x); t[5] = fast_tanh(c1.y);
    t[6] = fast_tanh(c1.z); t[7] = fast_tanh(c1.w);

#pragma unroll
    for (int r = 0; r < 25; ++r) {
      const float* wr = wbase + r * NIN + k0;   // wave-uniform -> scalar loads
#pragma unroll
      for (int j = 0; j < 8; ++j)
        acc[r] = fmaf(t[j], wr[j], acc[r]);
    }
    c0 = n0; c1 = n1;
  }

  float* Prow = P + (size_t)row * NRES + rb;
#pragma unroll
  for (int r = 0; r < 25; ++r) unsafeAtomicAdd(&Prow[r], acc[r]);
}

// ---- kernel 2: sequential recurrence (one wave per batch row) + fused readout ----
// lane r holds state[r] and W_res row r in registers; broadcast via v_readlane.
// P arrives from other XCDs (Infinity Cache, ~500-700 cyc) -> 8-deep register
// prefetch ring keeps 8 loads outstanding so the serial chain never waits.
__global__ __launch_bounds__(64) void recur_kernel(const float* __restrict__ P,
                                                   const float* __restrict__ W_res,
                                                   const float* __restrict__ W_out,
                                                   const float* __restrict__ bias,
                                                   float* __restrict__ out) {
  const int b    = blockIdx.x;
  const int lane = threadIdx.x;
  const int r    = (lane < NRES) ? lane : 0;   // lanes 50-63 mirror lane 0 (never read back)

  float w[NRES];
#pragma unroll
  for (int j = 0; j < NRES; ++j) w[j] = W_res[r * NRES + j];

  const float* Pb = P + (size_t)b * TSTEPS * NRES;
  float state = 0.0f;

  float pring[8];
#pragma unroll
  for (int i = 0; i < 8; ++i) pring[i] = Pb[i * NRES + r];

#pragma unroll 8
  for (int t = 0; t < TSTEPS; ++t) {
    float pcur = pring[t & 7];
    if (t + 8 < TSTEPS) pring[t & 7] = Pb[(t + 8) * NRES + r];

    // 4-way split accumulator to shorten the serial FMA chain
    float a0 = pcur, a1 = 0.0f, a2 = 0.0f, a3 = 0.0f;
#pragma unroll
    for (int j = 0; j < 48; j += 4) {
      float s0 = __uint_as_float(__builtin_amdgcn_readlane(__float_as_uint(state), j + 0));
      float s1 = __uint_as_float(__builtin_amdgcn_readlane(__float_as_uint(state), j + 1));
      float s2 = __uint_as_float(__builtin_amdgcn_readlane(__float_as_uint(state), j + 2));
      float s3 = __uint_as_float(__builtin_amdgcn_readlane(__float_as_uint(state), j + 3));
      a0 = fmaf(s0, w[j + 0], a0);
      a1 = fmaf(s1, w[j + 1], a1);
      a2 = fmaf(s2, w[j + 2], a2);
      a3 = fmaf(s3, w[j + 3], a3);
    }
    {
      float s0 = __uint_as_float(__builtin_amdgcn_readlane(__float_as_uint(state), 48));
      float s1 = __uint_as_float(__builtin_amdgcn_readlane(__float_as_uint(state), 49));
      a0 = fmaf(s0, w[48], a0);
      a1 = fmaf(s1, w[49], a1);
    }
    state = fast_tanh((a0 + a1) + (a2 + a3));
  }

  // readout: out[b][o] = tanh(sum_j state[j] * W_out[j][o] + bias[o])
#pragma unroll
  for (int kk = 0; kk < 8; ++kk) {
    int o = kk * 64 + lane;
    if (o < NOUT) {
      float a0 = bias[o];
      float a1 = 0.0f;
#pragma unroll
      for (int j = 0; j < NRES; j += 2) {
        float s0 = __uint_as_float(__builtin_amdgcn_readlane(__float_as_uint(state), j));
        float s1 = __uint_as_float(__builtin_amdgcn_readlane(__float_as_uint(state), j + 1));
        a0 = fmaf(s0, W_out[j * NOUT + o], a0);
        a1 = fmaf(s1, W_out[(j + 1) * NOUT + o], a1);
      }
      out[b * NOUT + o] = fast_tanh(a0 + a1);
    }
  }
}

extern "C" void kernel_launch(void* const* d_in, const int* in_sizes, int n_in,
                              void* d_out, int out_size, void* d_ws, size_t ws_size,
                              hipStream_t stream) {
  const float* inputs = (const float*)d_in[0];
  const float* W_in   = (const float*)d_in[1];
  const float* W_res  = (const float*)d_in[2];
  const float* W_out  = (const float*)d_in[3];
  const float* bias   = (const float*)d_in[4];
  float* out = (float*)d_out;

  // ws layout: P (f32 [32768][50]) at offset 0 — 6.55 MB
  float* P = (float*)d_ws;

  const int n4 = BT * NRES / 4;  // 409600 float4s
  zero_kernel<<<(n4 + 255) / 256, 256, 0, stream>>>((float4*)P, n4);
  proj_kernel<<<dim3(BT / 128, KSPLIT), 256, 0, stream>>>(inputs, W_in, P);
  recur_kernel<<<NBATCH, 64, 0, stream>>>(P, W_res, W_out, bias, out);
}